// Round 4
// baseline (87.141 us; speedup 1.0000x reference)
//
#include <hip/hip_runtime.h>
#include <math.h>
#include <float.h>

// LearnedRouter: B=4, S=4096, D=1024, N=256, TOPK=8
// Outputs (concat, fp32): token_repr[B,S,D], bank_indices[B,S], weights[B,S,N], topk_idx[B,S,8]

namespace {
constexpr int kB = 4, kS = 4096, kD = 1024, kN = 256, kK = 8;
constexpr float kScale = 0.03125f;   // 1/sqrt(1024)
constexpr float kNeg = -1e9f;
constexpr float kLog2e = 1.4426950408889634f;
constexpr size_t kBankOff = (size_t)kB * kS * kD;            // 16777216
constexpr size_t kWOff    = kBankOff + (size_t)kB * kS;      // 16793600
constexpr size_t kTopkOff = kWOff + (size_t)kB * kS * kN;    // 20987904
constexpr int kEC = 8;           // e-chunks (K-split) in k_prep
constexpr int kEL = kD / kEC;    // 128 e per chunk
constexpr int kNT = kN / 8;      // 32 n-tiles of 8 rows
}

#if __has_builtin(__builtin_amdgcn_exp2f)
#define FAST_EXP2(x) __builtin_amdgcn_exp2f(x)
#else
#define FAST_EXP2(x) exp2f(x)
#endif
#if __has_builtin(__builtin_amdgcn_rcpf)
#define FAST_RCP(x) __builtin_amdgcn_rcpf(x)
#else
#define FAST_RCP(x) (1.0f / (x))
#endif

// ---------------------------------------------------------------------------
// k_prep: partial[ec][n][d] = sum_{e in chunk ec} dr[n,e] * Wq[e,d]
// Grid (32 n-tiles, 8 e-chunks) x 256 thr. Thread owns 8 n x 4 d (float4).
// Partials land in d_out's weights region, overwritten later by k_main.
// ---------------------------------------------------------------------------
__global__ __launch_bounds__(256) void k_prep(const float* __restrict__ dr,
                                              const float* __restrict__ wq,
                                              float* __restrict__ part) {
  const int nt = blockIdx.x, ec = blockIdx.y, t = threadIdx.x;
  const float4* wq4 = reinterpret_cast<const float4*>(wq);   // [e][256]
  float4 acc[8];
#pragma unroll
  for (int j = 0; j < 8; ++j) acc[j] = make_float4(0.f, 0.f, 0.f, 0.f);
  const int e0 = ec * kEL;
#pragma unroll 4
  for (int e = e0; e < e0 + kEL; ++e) {
    const float4 wv = wq4[(size_t)e * (kD / 4) + t];
#pragma unroll
    for (int j = 0; j < 8; ++j) {
      const float a = dr[(size_t)(nt * 8 + j) * kD + e];   // uniform -> s_load
      acc[j].x += a * wv.x; acc[j].y += a * wv.y;
      acc[j].z += a * wv.z; acc[j].w += a * wv.w;
    }
  }
  float4* p4 = reinterpret_cast<float4*>(part);
#pragma unroll
  for (int j = 0; j < 8; ++j)
    p4[((size_t)ec * kN + nt * 8 + j) * (kD / 4) + t] = acc[j];
}

// ---------------------------------------------------------------------------
// k_reduce: R[n][d] = kScale * sum_ec partial[ec][n][d];  bias[n] likewise.
// ---------------------------------------------------------------------------
__global__ __launch_bounds__(256) void k_reduce(const float* __restrict__ part,
                                                const float* __restrict__ dr,
                                                const float* __restrict__ bq,
                                                float* __restrict__ R,
                                                float* __restrict__ bias) {
  const int n = blockIdx.x, t = threadIdx.x;
  const float4* p4 = reinterpret_cast<const float4*>(part);
  float4 a = make_float4(0.f, 0.f, 0.f, 0.f);
#pragma unroll
  for (int ec = 0; ec < kEC; ++ec) {
    const float4 p = p4[((size_t)ec * kN + n) * (kD / 4) + t];
    a.x += p.x; a.y += p.y; a.z += p.z; a.w += p.w;
  }
  a.x *= kScale; a.y *= kScale; a.z *= kScale; a.w *= kScale;
  reinterpret_cast<float4*>(R)[(size_t)n * (kD / 4) + t] = a;

  if (t < 64) {
    const float4* b4 = reinterpret_cast<const float4*>(bq);
    const float4* dr4 = reinterpret_cast<const float4*>(dr + (size_t)n * kD);
    float p = 0.f;
#pragma unroll
    for (int i = 0; i < 4; ++i) {
      const float4 bb = b4[t * 4 + i];
      const float4 dd = dr4[t * 4 + i];
      p += bb.x * dd.x + bb.y * dd.y + bb.z * dd.z + bb.w * dd.w;
    }
#pragma unroll
    for (int off = 32; off; off >>= 1) p += __shfl_xor(p, off);
    if (t == 0) bias[n] = p * kScale;
  }
}

// ---------------------------------------------------------------------------
// k_main: one block per token position s; wave w = batch w (t2s is [S,K],
// batch-independent -> 4-way sharing). 8 R-rows staged in 32KB LDS once per
// block; ss chunks prefetched 2-deep; scalarized control; exp2/rcp softmax;
// Batcher-19 sort only for topk_idx.
// ---------------------------------------------------------------------------
__global__ __launch_bounds__(256, 3) void k_main(const float* __restrict__ ts,
                                                 const float* __restrict__ ss,
                                                 const int* __restrict__ t2s,
                                                 const float* __restrict__ R,
                                                 const float* __restrict__ bias,
                                                 const float* __restrict__ temp_p,
                                                 float* __restrict__ out) {
  const int lane = threadIdx.x & 63;
  const int wvb = threadIdx.x >> 6;            // wave index == batch
  const int bid = blockIdx.x;
  // XCD-contiguous s chunks (default dispatch round-robins XCDs on bid&7)
  const int s = __builtin_amdgcn_readfirstlane(((bid & 7) << 9) | (bid >> 3));

  __shared__ float4 lr[kK * 256];              // 8 R-rows, 32 KB

  // --- routing indices (SALU/SMEM, identical across waves) ---
  int nraw[kK], nk[kK];
#pragma unroll
  for (int k = 0; k < kK; ++k) {
    nraw[k] = t2s[s * kK + k];
    const int n = nraw[k];
    nk[k] = n < 0 ? 0 : (n > kN - 1 ? kN - 1 : n);
  }
  int validmask = 0;
#pragma unroll
  for (int k = 0; k < kK; ++k) {
    bool v = (nraw[k] >= 0);
#pragma unroll
    for (int j = 0; j < kK; ++j)
      if (j < k && nk[j] == nk[k]) v = false;
    validmask |= v ? (1 << k) : 0;
  }

  // --- cooperative R staging: group g=t>>5 stages row g (static-select) ---
  {
    const int rk = threadIdx.x >> 5, rc = threadIdx.x & 31;
    int myrow = nk[0];
#pragma unroll
    for (int k = 1; k < kK; ++k) myrow = (rk == k) ? nk[k] : myrow;
    const float4* R4 = reinterpret_cast<const float4*>(R);
#pragma unroll
    for (int j = 0; j < 8; ++j)
      lr[rk * 256 + rc + 32 * j] = R4[(size_t)myrow * 256 + rc + 32 * j];
  }

  // --- ss prefetch (chunks 0,1) + token row, issued before the dot phase ---
  const float4* ssb = reinterpret_cast<const float4*>(ss) + (size_t)wvb * kN * (kD / 4);
  float4 c0[kK], c1[kK];
#pragma unroll
  for (int k = 0; k < kK; ++k) c0[k] = ssb[(size_t)nk[k] * (kD / 4) + lane];
#pragma unroll
  for (int k = 0; k < kK; ++k) c1[k] = ssb[(size_t)nk[k] * (kD / 4) + 64 + lane];

  const size_t row = (size_t)wvb * kS + s;
  const float4* t4 = reinterpret_cast<const float4*>(ts) + row * (kD / 4);
  const float4 tv0 = t4[lane];
  const float4 tv1 = t4[64 + lane];
  const float4 tv2 = t4[128 + lane];
  const float4 tv3 = t4[192 + lane];

  __syncthreads();

  // --- 8 dots vs LDS R rows ---
  float pk[kK];
#pragma unroll
  for (int k = 0; k < kK; ++k) {
    const float4 r0 = lr[k * 256 + lane];
    const float4 r1 = lr[k * 256 + 64 + lane];
    const float4 r2 = lr[k * 256 + 128 + lane];
    const float4 r3 = lr[k * 256 + 192 + lane];
    float a = tv0.x * r0.x + tv0.y * r0.y + tv0.z * r0.z + tv0.w * r0.w;
    a += tv1.x * r1.x + tv1.y * r1.y + tv1.z * r1.z + tv1.w * r1.w;
    a += tv2.x * r2.x + tv2.y * r2.y + tv2.z * r2.z + tv2.w * r2.w;
    a += tv3.x * r3.x + tv3.y * r3.y + tv3.z * r3.z + tv3.w * r3.w;
    pk[k] = a;
  }
#pragma unroll
  for (int k = 0; k < kK; ++k) {
    float a = pk[k];
    a += __shfl_xor(a, 1);
    a += __shfl_xor(a, 2);
    a += __shfl_xor(a, 4);
    a += __shfl_xor(a, 8);
    a += __shfl_xor(a, 16);
    a += __shfl_xor(a, 32);
    pk[k] = a + bias[nk[k]];
  }

  // --- softmax over valid slots ---
  float mx = -INFINITY;
#pragma unroll
  for (int k = 0; k < kK; ++k)
    mx = fmaxf(mx, ((validmask >> k) & 1) ? pk[k] : -INFINITY);
  const float it = kLog2e * FAST_RCP(fmaxf(temp_p[0], 0.5f));
  float w[kK];
  float denom = 0.f;
#pragma unroll
  for (int k = 0; k < kK; ++k) {
    const float e = ((validmask >> k) & 1) ? FAST_EXP2((pk[k] - mx) * it) : 0.f;
    w[k] = e;
    denom += e;
  }
  const float rd = FAST_RCP(denom);
#pragma unroll
  for (int k = 0; k < kK; ++k) w[k] *= rd;

  // --- weights row [N] ---
  {
    const int cb = lane * 4;
    float4 wvv = make_float4(0.f, 0.f, 0.f, 0.f);
#pragma unroll
    for (int k = 0; k < kK; ++k) {
      const bool vb = (validmask >> k) & 1;
      wvv.x = (vb && nk[k] == cb    ) ? w[k] : wvv.x;
      wvv.y = (vb && nk[k] == cb + 1) ? w[k] : wvv.y;
      wvv.z = (vb && nk[k] == cb + 2) ? w[k] : wvv.z;
      wvv.w = (vb && nk[k] == cb + 3) ? w[k] : wvv.w;
    }
    reinterpret_cast<float4*>(out + kWOff)[row * (kN / 4) + lane] = wvv;
  }

  // --- token_repr: 2-deep pipelined chunks ---
  float4* o4 = reinterpret_cast<float4*>(out) + row * (kD / 4);
  {
    float4 acc = make_float4(0.f, 0.f, 0.f, 0.f);
#pragma unroll
    for (int k = 0; k < kK; ++k) {
      acc.x += w[k] * c0[k].x; acc.y += w[k] * c0[k].y;
      acc.z += w[k] * c0[k].z; acc.w += w[k] * c0[k].w;
    }
    o4[lane] = acc;
  }
  float4 c2[kK];
#pragma unroll
  for (int k = 0; k < kK; ++k) c2[k] = ssb[(size_t)nk[k] * (kD / 4) + 128 + lane];
  {
    float4 acc = make_float4(0.f, 0.f, 0.f, 0.f);
#pragma unroll
    for (int k = 0; k < kK; ++k) {
      acc.x += w[k] * c1[k].x; acc.y += w[k] * c1[k].y;
      acc.z += w[k] * c1[k].z; acc.w += w[k] * c1[k].w;
    }
    o4[64 + lane] = acc;
  }
  float4 c3[kK];
#pragma unroll
  for (int k = 0; k < kK; ++k) c3[k] = ssb[(size_t)nk[k] * (kD / 4) + 192 + lane];
  {
    float4 acc = make_float4(0.f, 0.f, 0.f, 0.f);
#pragma unroll
    for (int k = 0; k < kK; ++k) {
      acc.x += w[k] * c2[k].x; acc.y += w[k] * c2[k].y;
      acc.z += w[k] * c2[k].z; acc.w += w[k] * c2[k].w;
    }
    o4[128 + lane] = acc;
  }
  {
    float4 acc = make_float4(0.f, 0.f, 0.f, 0.f);
#pragma unroll
    for (int k = 0; k < kK; ++k) {
      acc.x += w[k] * c3[k].x; acc.y += w[k] * c3[k].y;
      acc.z += w[k] * c3[k].z; acc.w += w[k] * c3[k].w;
    }
    o4[192 + lane] = acc;
  }

  // --- fill indices: smallest absent set ids (SALU, 4x u64 presence mask) ---
  unsigned long long pm0 = 0, pm1 = 0, pm2 = 0, pm3 = 0;
#pragma unroll
  for (int k = 0; k < kK; ++k) {
    const bool v = (validmask >> k) & 1;
    const unsigned long long bit = 1ull << (nk[k] & 63);
    const int wd = nk[k] >> 6;
    pm0 |= (v && wd == 0) ? bit : 0ull;
    pm1 |= (v && wd == 1) ? bit : 0ull;
    pm2 |= (v && wd == 2) ? bit : 0ull;
    pm3 |= (v && wd == 3) ? bit : 0ull;
  }
  int seq[kK];
#pragma unroll
  for (int i = 0; i < kK; ++i) {
    const unsigned long long i0 = ~pm0, i1 = ~pm1, i2 = ~pm2, i3 = ~pm3;
    const int c = i0 ? (__ffsll(i0) - 1)
                     : (i1 ? 64 + (__ffsll(i1) - 1)
                           : (i2 ? 128 + (__ffsll(i2) - 1)
                                 : 192 + (__ffsll(i3) - 1)));
    seq[i] = c;
    const unsigned long long b2 = 1ull << (c & 63);
    const int wd = c >> 6;
    pm0 |= (wd == 0) ? b2 : 0ull;
    pm1 |= (wd == 1) ? b2 : 0ull;
    pm2 |= (wd == 2) ? b2 : 0ull;
    pm3 |= (wd == 3) ? b2 : 0ull;
  }

  // --- merge fills, Batcher-19 sort (desc score, asc idx) for topk only ---
  float fs[kK];
  int fi[kK];
#pragma unroll
  for (int k = 0; k < kK; ++k) {
    const bool v = (validmask >> k) & 1;
    const int jk = __popc((~validmask) & ((1 << k) - 1));
    int fv = seq[0];
#pragma unroll
    for (int j = 1; j < kK; ++j) fv = (jk == j) ? seq[j] : fv;
    fs[k] = v ? pk[k] : kNeg;
    fi[k] = v ? nk[k] : fv;
  }
#define CE(A, B)                                                        \
  {                                                                     \
    const bool sw = (fs[B] > fs[A]) || (fs[B] == fs[A] && fi[B] < fi[A]); \
    const float fa = fs[A], fb = fs[B];                                 \
    const int ia = fi[A], ib = fi[B];                                   \
    fs[A] = sw ? fb : fa; fs[B] = sw ? fa : fb;                         \
    fi[A] = sw ? ib : ia; fi[B] = sw ? ia : ib;                         \
  }
  CE(0,1) CE(2,3) CE(4,5) CE(6,7)
  CE(0,2) CE(1,3) CE(4,6) CE(5,7)
  CE(1,2) CE(5,6)
  CE(0,4) CE(1,5) CE(2,6) CE(3,7)
  CE(2,4) CE(3,5)
  CE(1,2) CE(3,4) CE(5,6)
#undef CE

  if (lane < kK) {
    int v = fi[0];
#pragma unroll
    for (int k = 1; k < kK; ++k) v = (lane == k) ? fi[k] : v;
    out[kTopkOff + row * kK + lane] = (float)v;
  }
  if (lane == 0) out[kBankOff + row] = (float)fi[0];
}

extern "C" void kernel_launch(void* const* d_in, const int* in_sizes, int n_in,
                              void* d_out, int out_size, void* d_ws, size_t ws_size,
                              hipStream_t stream) {
  const float* ts  = (const float*)d_in[0];   // token_states [4,4096,1024]
  const float* ss  = (const float*)d_in[1];   // set_states   [4,256,1024]
  const float* dr  = (const float*)d_in[2];   // desc_router  [256,1024]
  const int*   t2s = (const int*)  d_in[3];   // token_to_sets[4096,8]
  const float* wq  = (const float*)d_in[4];   // Wq [1024,1024]
  const float* bq  = (const float*)d_in[5];   // bq [1024]
  const float* tmp = (const float*)d_in[6];   // temperature [1]
  float* out = (float*)d_out;

  float* R    = (float*)d_ws;                 // 256*1024 f32 = 1 MiB
  float* bias = R + (size_t)kN * kD;          // 256 f32
  float* part = out + kWOff;                  // 8 MiB partials, overwritten by
                                              // k_main's weights write later

  k_prep<<<dim3(kNT, kEC), 256, 0, stream>>>(dr, wq, part);
  k_reduce<<<kN, 256, 0, stream>>>(part, dr, bq, R, bias);
  k_main<<<kS, 256, 0, stream>>>(ts, ss, t2s, R, bias, tmp, out);
}

// Round 5
// 81.273 us; speedup vs baseline: 1.0722x; 1.0722x over previous
//
#include <hip/hip_runtime.h>
#include <math.h>
#include <float.h>

// LearnedRouter: B=4, S=4096, D=1024, N=256, TOPK=8
// Outputs (concat, fp32): token_repr[B,S,D], bank_indices[B,S], weights[B,S,N], topk_idx[B,S,8]

namespace {
constexpr int kB = 4, kS = 4096, kD = 1024, kN = 256, kK = 8;
constexpr float kScale = 0.03125f;   // 1/sqrt(1024)
constexpr float kNeg = -1e9f;
constexpr float kLog2e = 1.4426950408889634f;
constexpr size_t kBankOff = (size_t)kB * kS * kD;            // 16777216
constexpr size_t kWOff    = kBankOff + (size_t)kB * kS;      // 16793600
constexpr size_t kTopkOff = kWOff + (size_t)kB * kS * kN;    // 20987904
constexpr int kEC = 8;           // e-chunks (K-split) in k_prep
constexpr int kEL = kD / kEC;    // 128 e per chunk
constexpr int kNT = kN / 8;      // 32 n-tiles of 8 rows
}

#if __has_builtin(__builtin_amdgcn_exp2f)
#define FAST_EXP2(x) __builtin_amdgcn_exp2f(x)
#else
#define FAST_EXP2(x) exp2f(x)
#endif
#if __has_builtin(__builtin_amdgcn_rcpf)
#define FAST_RCP(x) __builtin_amdgcn_rcpf(x)
#else
#define FAST_RCP(x) (1.0f / (x))
#endif

// ---------------------------------------------------------------------------
// k_prep: partial[ec][n][d] = sum_{e in chunk ec} dr[n,e] * Wq[e,d]
// Grid (32 n-tiles, 8 e-chunks) x 256 thr. Thread owns 8 n x 4 d (float4).
// Partials land in d_out's weights region, overwritten later by k_repr.
// ---------------------------------------------------------------------------
__global__ __launch_bounds__(256) void k_prep(const float* __restrict__ dr,
                                              const float* __restrict__ wq,
                                              float* __restrict__ part) {
  const int nt = blockIdx.x, ec = blockIdx.y, t = threadIdx.x;
  const float4* wq4 = reinterpret_cast<const float4*>(wq);   // [e][256]
  float4 acc[8];
#pragma unroll
  for (int j = 0; j < 8; ++j) acc[j] = make_float4(0.f, 0.f, 0.f, 0.f);
  const int e0 = ec * kEL;
#pragma unroll 4
  for (int e = e0; e < e0 + kEL; ++e) {
    const float4 wv = wq4[(size_t)e * (kD / 4) + t];
#pragma unroll
    for (int j = 0; j < 8; ++j) {
      const float a = dr[(size_t)(nt * 8 + j) * kD + e];   // uniform -> s_load
      acc[j].x += a * wv.x; acc[j].y += a * wv.y;
      acc[j].z += a * wv.z; acc[j].w += a * wv.w;
    }
  }
  float4* p4 = reinterpret_cast<float4*>(part);
#pragma unroll
  for (int j = 0; j < 8; ++j)
    p4[((size_t)ec * kN + nt * 8 + j) * (kD / 4) + t] = acc[j];
}

// ---------------------------------------------------------------------------
// k_reduce: R[n][d] = kScale * sum_ec partial[ec][n][d];  bias[n] likewise.
// ---------------------------------------------------------------------------
__global__ __launch_bounds__(256) void k_reduce(const float* __restrict__ part,
                                                const float* __restrict__ dr,
                                                const float* __restrict__ bq,
                                                float* __restrict__ R,
                                                float* __restrict__ bias) {
  const int n = blockIdx.x, t = threadIdx.x;
  const float4* p4 = reinterpret_cast<const float4*>(part);
  float4 a = make_float4(0.f, 0.f, 0.f, 0.f);
#pragma unroll
  for (int ec = 0; ec < kEC; ++ec) {
    const float4 p = p4[((size_t)ec * kN + n) * (kD / 4) + t];
    a.x += p.x; a.y += p.y; a.z += p.z; a.w += p.w;
  }
  a.x *= kScale; a.y *= kScale; a.z *= kScale; a.w *= kScale;
  reinterpret_cast<float4*>(R)[(size_t)n * (kD / 4) + t] = a;

  if (t < 64) {
    const float4* b4 = reinterpret_cast<const float4*>(bq);
    const float4* dr4 = reinterpret_cast<const float4*>(dr + (size_t)n * kD);
    float p = 0.f;
#pragma unroll
    for (int i = 0; i < 4; ++i) {
      const float4 bb = b4[t * 4 + i];
      const float4 dd = dr4[t * 4 + i];
      p += bb.x * dd.x + bb.y * dd.y + bb.z * dd.z + bb.w * dd.w;
    }
#pragma unroll
    for (int off = 32; off; off >>= 1) p += __shfl_xor(p, off);
    if (t == 0) bias[n] = p * kScale;
  }
}

// ---------------------------------------------------------------------------
// k_score: one wave per token, batch tied to XCD pair (L2-resident R).
// Dots vs gathered R rows, SALU dedup/fills, Batcher-19 sort, softmax on
// SORTED scores (slot0 = max). Writes topk_idx + bank + 64B state record.
// ---------------------------------------------------------------------------
__global__ __launch_bounds__(256) void k_score(const float* __restrict__ ts,
                                               const int* __restrict__ t2s,
                                               const float* __restrict__ R,
                                               const float* __restrict__ bias,
                                               const float* __restrict__ temp_p,
                                               int* __restrict__ st,
                                               float* __restrict__ out) {
  const int lane = threadIdx.x & 63;
  const int wid = threadIdx.x >> 6;
  const int bid = blockIdx.x;
  // XCD pair (2b,2b+1) owns batch b; R (1 MiB) L2-resident on every XCD.
  const int xcd = bid & 7;
  const int b = xcd >> 1;
  int s_ = ((bid >> 3) << 2) + wid + ((xcd & 1) << 11);
  const int s = __builtin_amdgcn_readfirstlane(s_);
  const size_t row = (size_t)b * kS + s;

  // --- routing indices (SALU/SMEM) ---
  int nraw[kK], nk[kK];
#pragma unroll
  for (int k = 0; k < kK; ++k) {
    nraw[k] = t2s[s * kK + k];
    const int n = nraw[k];
    nk[k] = n < 0 ? 0 : (n > kN - 1 ? kN - 1 : n);
  }
  int validmask = 0;
#pragma unroll
  for (int k = 0; k < kK; ++k) {
    bool v = (nraw[k] >= 0);
#pragma unroll
    for (int j = 0; j < kK; ++j)
      if (j < k && nk[j] == nk[k]) v = false;
    validmask |= v ? (1 << k) : 0;
  }
  const int cnt = __popc(validmask);

  // --- token row (4 coalesced 4KB loads) ---
  const float4* t4 = reinterpret_cast<const float4*>(ts) + row * (kD / 4);
  const float4 tv0 = t4[lane];
  const float4 tv1 = t4[64 + lane];
  const float4 tv2 = t4[128 + lane];
  const float4 tv3 = t4[192 + lane];

  // --- 8 full-wave dots vs R (SGPR base + lane offset), butterfly reduce ---
  float pk[kK];
#pragma unroll
  for (int k = 0; k < kK; ++k) {
    const float4* r4 = reinterpret_cast<const float4*>(R) + (size_t)nk[k] * (kD / 4);
    const float4 r0 = r4[lane];
    const float4 r1 = r4[64 + lane];
    const float4 r2 = r4[128 + lane];
    const float4 r3 = r4[192 + lane];
    float a = tv0.x * r0.x + tv0.y * r0.y + tv0.z * r0.z + tv0.w * r0.w;
    a += tv1.x * r1.x + tv1.y * r1.y + tv1.z * r1.z + tv1.w * r1.w;
    a += tv2.x * r2.x + tv2.y * r2.y + tv2.z * r2.z + tv2.w * r2.w;
    a += tv3.x * r3.x + tv3.y * r3.y + tv3.z * r3.z + tv3.w * r3.w;
    pk[k] = a;
  }
#pragma unroll
  for (int k = 0; k < kK; ++k) {
    float a = pk[k];
    a += __shfl_xor(a, 1);
    a += __shfl_xor(a, 2);
    a += __shfl_xor(a, 4);
    a += __shfl_xor(a, 8);
    a += __shfl_xor(a, 16);
    a += __shfl_xor(a, 32);
    pk[k] = a + bias[nk[k]];
  }

  // --- fill indices: smallest absent set ids (SALU, 4x u64 presence mask) ---
  unsigned long long pm0 = 0, pm1 = 0, pm2 = 0, pm3 = 0;
#pragma unroll
  for (int k = 0; k < kK; ++k) {
    const bool v = (validmask >> k) & 1;
    const unsigned long long bit = 1ull << (nk[k] & 63);
    const int wd = nk[k] >> 6;
    pm0 |= (v && wd == 0) ? bit : 0ull;
    pm1 |= (v && wd == 1) ? bit : 0ull;
    pm2 |= (v && wd == 2) ? bit : 0ull;
    pm3 |= (v && wd == 3) ? bit : 0ull;
  }
  int seq[kK];
#pragma unroll
  for (int i = 0; i < kK; ++i) {
    const unsigned long long i0 = ~pm0, i1 = ~pm1, i2 = ~pm2, i3 = ~pm3;
    const int c = i0 ? (__ffsll(i0) - 1)
                     : (i1 ? 64 + (__ffsll(i1) - 1)
                           : (i2 ? 128 + (__ffsll(i2) - 1)
                                 : 192 + (__ffsll(i3) - 1)));
    seq[i] = c;
    const unsigned long long b2 = 1ull << (c & 63);
    const int wd = c >> 6;
    pm0 |= (wd == 0) ? b2 : 0ull;
    pm1 |= (wd == 1) ? b2 : 0ull;
    pm2 |= (wd == 2) ? b2 : 0ull;
    pm3 |= (wd == 3) ? b2 : 0ull;
  }

  // --- merge fills, Batcher-19 sort (desc score, asc idx) ---
  float fs[kK];
  int fi[kK];
#pragma unroll
  for (int k = 0; k < kK; ++k) {
    const bool v = (validmask >> k) & 1;
    const int jk = __popc((~validmask) & ((1 << k) - 1));
    int fv = seq[0];
#pragma unroll
    for (int j = 1; j < kK; ++j) fv = (jk == j) ? seq[j] : fv;
    fs[k] = v ? pk[k] : kNeg;
    fi[k] = v ? nk[k] : fv;
  }
#define CE(A, B)                                                        \
  {                                                                     \
    const bool sw = (fs[B] > fs[A]) || (fs[B] == fs[A] && fi[B] < fi[A]); \
    const float fa = fs[A], fb = fs[B];                                 \
    const int ia = fi[A], ib = fi[B];                                   \
    fs[A] = sw ? fb : fa; fs[B] = sw ? fa : fb;                         \
    fi[A] = sw ? ib : ia; fi[B] = sw ? ia : ib;                         \
  }
  CE(0,1) CE(2,3) CE(4,5) CE(6,7)
  CE(0,2) CE(1,3) CE(4,6) CE(5,7)
  CE(1,2) CE(5,6)
  CE(0,4) CE(1,5) CE(2,6) CE(3,7)
  CE(2,4) CE(3,5)
  CE(1,2) CE(3,4) CE(5,6)
#undef CE

  // --- softmax directly on sorted scores (fs[0] = max, valid = first cnt) ---
  const float it = kLog2e * FAST_RCP(fmaxf(temp_p[0], 0.5f));
  float w[kK];
  float denom = 0.f;
#pragma unroll
  for (int i = 0; i < kK; ++i) {
    const float e = (i < cnt) ? FAST_EXP2((fs[i] - fs[0]) * it) : 0.f;
    w[i] = e;
    denom += e;
  }
  const float rd = FAST_RCP(denom);
#pragma unroll
  for (int i = 0; i < kK; ++i) w[i] *= rd;

  // --- outputs: topk_idx (lanes 0-7), bank (lane 0), state record (16 dw) ---
  if (lane < kK) {
    int v = fi[0];
#pragma unroll
    for (int k = 1; k < kK; ++k) v = (lane == k) ? fi[k] : v;
    out[kTopkOff + row * kK + lane] = (float)v;
  }
  if (lane == 0) out[kBankOff + row] = (float)fi[0];

  int sel = 0;
#pragma unroll
  for (int k = 0; k < kK; ++k) {
    sel = (lane == k) ? __float_as_int(w[k]) : sel;
    sel = (lane == k + kK) ? fi[k] : sel;
  }
  if (lane < 16) st[row * 16 + lane] = sel;
}

// ---------------------------------------------------------------------------
// k_repr: one wave per token. s_load 64B state -> 32 ss gathers (L2-local,
// batch per XCD pair) -> token_repr + weights row. Tiny VGPR, max occupancy.
// ---------------------------------------------------------------------------
__global__ __launch_bounds__(256) void k_repr(const float* __restrict__ ss,
                                              const int* __restrict__ st,
                                              float* __restrict__ out) {
  const int lane = threadIdx.x & 63;
  const int wid = threadIdx.x >> 6;
  const int bid = blockIdx.x;
  const int xcd = bid & 7;
  const int b = xcd >> 1;
  int s_ = ((bid >> 3) << 2) + wid + ((xcd & 1) << 11);
  const int s = __builtin_amdgcn_readfirstlane(s_);
  const size_t row = (size_t)b * kS + s;

  // state (wave-uniform -> scalar loads)
  float w[kK];
  int fi[kK];
#pragma unroll
  for (int k = 0; k < kK; ++k) {
    w[k] = __int_as_float(st[row * 16 + k]);
    fi[k] = st[row * 16 + kK + k];
  }

  const float4* ssb = reinterpret_cast<const float4*>(ss) + (size_t)b * kN * (kD / 4);
  float4* o4 = reinterpret_cast<float4*>(out) + row * (kD / 4);
#pragma unroll
  for (int c = 0; c < 4; ++c) {
    float4 v0 = ssb[(size_t)fi[0] * (kD / 4) + c * 64 + lane];
    float4 v1 = ssb[(size_t)fi[1] * (kD / 4) + c * 64 + lane];
    float4 v2 = ssb[(size_t)fi[2] * (kD / 4) + c * 64 + lane];
    float4 v3 = ssb[(size_t)fi[3] * (kD / 4) + c * 64 + lane];
    float4 v4 = ssb[(size_t)fi[4] * (kD / 4) + c * 64 + lane];
    float4 v5 = ssb[(size_t)fi[5] * (kD / 4) + c * 64 + lane];
    float4 v6 = ssb[(size_t)fi[6] * (kD / 4) + c * 64 + lane];
    float4 v7 = ssb[(size_t)fi[7] * (kD / 4) + c * 64 + lane];
    float4 acc;
    acc.x = w[0] * v0.x + w[1] * v1.x + w[2] * v2.x + w[3] * v3.x
          + w[4] * v4.x + w[5] * v5.x + w[6] * v6.x + w[7] * v7.x;
    acc.y = w[0] * v0.y + w[1] * v1.y + w[2] * v2.y + w[3] * v3.y
          + w[4] * v4.y + w[5] * v5.y + w[6] * v6.y + w[7] * v7.y;
    acc.z = w[0] * v0.z + w[1] * v1.z + w[2] * v2.z + w[3] * v3.z
          + w[4] * v4.z + w[5] * v5.z + w[6] * v6.z + w[7] * v7.z;
    acc.w = w[0] * v0.w + w[1] * v1.w + w[2] * v2.w + w[3] * v3.w
          + w[4] * v4.w + w[5] * v5.w + w[6] * v6.w + w[7] * v7.w;
    o4[c * 64 + lane] = acc;
  }

  // weights row [N]: float4 per lane (fillers carry w==0 -> correct zeros)
  {
    const int cb = lane * 4;
    float4 wv = make_float4(0.f, 0.f, 0.f, 0.f);
#pragma unroll
    for (int k = 0; k < kK; ++k) {
      wv.x = (fi[k] == cb    ) ? w[k] : wv.x;
      wv.y = (fi[k] == cb + 1) ? w[k] : wv.y;
      wv.z = (fi[k] == cb + 2) ? w[k] : wv.z;
      wv.w = (fi[k] == cb + 3) ? w[k] : wv.w;
    }
    reinterpret_cast<float4*>(out + kWOff)[row * (kN / 4) + lane] = wv;
  }
}

extern "C" void kernel_launch(void* const* d_in, const int* in_sizes, int n_in,
                              void* d_out, int out_size, void* d_ws, size_t ws_size,
                              hipStream_t stream) {
  const float* ts  = (const float*)d_in[0];   // token_states [4,4096,1024]
  const float* ss  = (const float*)d_in[1];   // set_states   [4,256,1024]
  const float* dr  = (const float*)d_in[2];   // desc_router  [256,1024]
  const int*   t2s = (const int*)  d_in[3];   // token_to_sets[4096,8]
  const float* wq  = (const float*)d_in[4];   // Wq [1024,1024]
  const float* bq  = (const float*)d_in[5];   // bq [1024]
  const float* tmp = (const float*)d_in[6];   // temperature [1]
  float* out = (float*)d_out;

  float* R    = (float*)d_ws;                 // 256*1024 f32 = 1 MiB
  float* bias = R + (size_t)kN * kD;          // 256 f32
  int*   st   = (int*)(bias + kN);            // 16384 x 16 dwords = 1 MiB
  float* part = out + kWOff;                  // 8 MiB partials, overwritten by
                                              // k_repr's weights write later

  k_prep<<<dim3(kNT, kEC), 256, 0, stream>>>(dr, wq, part);
  k_reduce<<<kN, 256, 0, stream>>>(part, dr, bq, R, bias);
  k_score<<<kB * kS / 4, 256, 0, stream>>>(ts, t2s, R, bias, tmp, st, out);
  k_repr<<<kB * kS / 4, 256, 0, stream>>>(ss, st, out);
}

// Round 6
// 77.800 us; speedup vs baseline: 1.1201x; 1.0446x over previous
//
#include <hip/hip_runtime.h>
#include <math.h>
#include <float.h>

// LearnedRouter: B=4, S=4096, D=1024, N=256, TOPK=8
// Outputs (concat, fp32): token_repr[B,S,D], bank_indices[B,S], weights[B,S,N], topk_idx[B,S,8]

namespace {
constexpr int kB = 4, kS = 4096, kD = 1024, kN = 256, kK = 8;
constexpr float kScale = 0.03125f;   // 1/sqrt(1024)
constexpr float kNeg = -1e9f;
constexpr float kLog2e = 1.4426950408889634f;
constexpr size_t kBankOff = (size_t)kB * kS * kD;            // 16777216
constexpr size_t kWOff    = kBankOff + (size_t)kB * kS;      // 16793600
constexpr size_t kTopkOff = kWOff + (size_t)kB * kS * kN;    // 20987904
constexpr int kEC = 8;           // e-chunks (K-split) in k_prep
constexpr int kEL = kD / kEC;    // 128 e per chunk
constexpr int kNT = kN / 8;      // 32 n-tiles of 8 rows
}

#if __has_builtin(__builtin_amdgcn_exp2f)
#define FAST_EXP2(x) __builtin_amdgcn_exp2f(x)
#else
#define FAST_EXP2(x) exp2f(x)
#endif
#if __has_builtin(__builtin_amdgcn_rcpf)
#define FAST_RCP(x) __builtin_amdgcn_rcpf(x)
#else
#define FAST_RCP(x) (1.0f / (x))
#endif

// ---------------------------------------------------------------------------
// k_prep: partial[ec][n][d] = sum_{e in chunk ec} dr[n,e] * Wq[e,d]
// Grid (32 n-tiles, 8 e-chunks) x 256 thr. Thread owns 8 n x 4 d (float4).
// Partials land in d_out's weights region, overwritten later by k_repr.
// ---------------------------------------------------------------------------
__global__ __launch_bounds__(256) void k_prep(const float* __restrict__ dr,
                                              const float* __restrict__ wq,
                                              float* __restrict__ part) {
  const int nt = blockIdx.x, ec = blockIdx.y, t = threadIdx.x;
  const float4* wq4 = reinterpret_cast<const float4*>(wq);   // [e][256]
  float4 acc[8];
#pragma unroll
  for (int j = 0; j < 8; ++j) acc[j] = make_float4(0.f, 0.f, 0.f, 0.f);
  const int e0 = ec * kEL;
#pragma unroll 4
  for (int e = e0; e < e0 + kEL; ++e) {
    const float4 wv = wq4[(size_t)e * (kD / 4) + t];
#pragma unroll
    for (int j = 0; j < 8; ++j) {
      const float a = dr[(size_t)(nt * 8 + j) * kD + e];   // uniform -> s_load
      acc[j].x += a * wv.x; acc[j].y += a * wv.y;
      acc[j].z += a * wv.z; acc[j].w += a * wv.w;
    }
  }
  float4* p4 = reinterpret_cast<float4*>(part);
#pragma unroll
  for (int j = 0; j < 8; ++j)
    p4[((size_t)ec * kN + nt * 8 + j) * (kD / 4) + t] = acc[j];
}

// ---------------------------------------------------------------------------
// k_reduce: R[n][d] = kScale * sum_ec partial[ec][n][d];  bias[n] likewise.
// ---------------------------------------------------------------------------
__global__ __launch_bounds__(256) void k_reduce(const float* __restrict__ part,
                                                const float* __restrict__ dr,
                                                const float* __restrict__ bq,
                                                float* __restrict__ R,
                                                float* __restrict__ bias) {
  const int n = blockIdx.x, t = threadIdx.x;
  const float4* p4 = reinterpret_cast<const float4*>(part);
  float4 a = make_float4(0.f, 0.f, 0.f, 0.f);
#pragma unroll
  for (int ec = 0; ec < kEC; ++ec) {
    const float4 p = p4[((size_t)ec * kN + n) * (kD / 4) + t];
    a.x += p.x; a.y += p.y; a.z += p.z; a.w += p.w;
  }
  a.x *= kScale; a.y *= kScale; a.z *= kScale; a.w *= kScale;
  reinterpret_cast<float4*>(R)[(size_t)n * (kD / 4) + t] = a;

  if (t < 64) {
    const float4* b4 = reinterpret_cast<const float4*>(bq);
    const float4* dr4 = reinterpret_cast<const float4*>(dr + (size_t)n * kD);
    float p = 0.f;
#pragma unroll
    for (int i = 0; i < 4; ++i) {
      const float4 bb = b4[t * 4 + i];
      const float4 dd = dr4[t * 4 + i];
      p += bb.x * dd.x + bb.y * dd.y + bb.z * dd.z + bb.w * dd.w;
    }
#pragma unroll
    for (int off = 32; off; off >>= 1) p += __shfl_xor(p, off);
    if (t == 0) bias[n] = p * kScale;
  }
}

// ---------------------------------------------------------------------------
// k_score v2: ONE WAVE PER TOKEN POSITION, all 4 batches in-wave
// (group g = lanes 16g..16g+15 = batch g). t2s is [S,K] so nk/valid/fill are
// shared; R-row addresses depend only on u=lane&15 -> the 4 groups read
// identical addresses (TA dedup => R L2 traffic /4, no LDS). Tail
// (sort/fill/softmax) runs once per wave covering 4 tokens. 4096 waves.
// ---------------------------------------------------------------------------
__global__ __launch_bounds__(256, 4) void k_score(const float* __restrict__ ts,
                                                  const int* __restrict__ t2s,
                                                  const float* __restrict__ R,
                                                  const float* __restrict__ bias,
                                                  const float* __restrict__ temp_p,
                                                  int* __restrict__ st,
                                                  float* __restrict__ out) {
  const int lane = threadIdx.x & 63;
  const int wid = threadIdx.x >> 6;
  const int u = lane & 15;     // d-slice lane within group
  const int g = lane >> 4;     // batch
  const int s = __builtin_amdgcn_readfirstlane(blockIdx.x * 4 + wid);

  // --- routing indices (SALU/SMEM, shared by all 4 batches) ---
  int nraw[kK], nk[kK];
#pragma unroll
  for (int k = 0; k < kK; ++k) {
    nraw[k] = t2s[s * kK + k];
    const int n = nraw[k];
    nk[k] = n < 0 ? 0 : (n > kN - 1 ? kN - 1 : n);
  }
  int validmask = 0;
#pragma unroll
  for (int k = 0; k < kK; ++k) {
    bool v = (nraw[k] >= 0);
#pragma unroll
    for (int j = 0; j < kK; ++j)
      if (j < k && nk[j] == nk[k]) v = false;
    validmask |= v ? (1 << k) : 0;
  }
  const int cnt = __popc(validmask);

  // --- dots: group g computes ts[g,s,:] . R[nk[k],:] for all 8 k ---
  const float4* ts4 = reinterpret_cast<const float4*>(ts);
  const float4* R4 = reinterpret_cast<const float4*>(R);
  const size_t tbase = ((size_t)g * kS + s) * (kD / 4) + u;
  float acc[kK];
#pragma unroll
  for (int k = 0; k < kK; ++k) acc[k] = 0.f;
#pragma unroll 2
  for (int i = 0; i < 16; ++i) {
    const float4 tv = ts4[tbase + i * 16];
#pragma unroll
    for (int k = 0; k < kK; ++k) {
      const float4 rv = R4[(size_t)nk[k] * (kD / 4) + i * 16 + u];
      acc[k] += tv.x * rv.x + tv.y * rv.y + tv.z * rv.z + tv.w * rv.w;
    }
  }

  // --- 4-level butterfly within 16-lane group; then bias ---
  float pk[kK];
#pragma unroll
  for (int k = 0; k < kK; ++k) {
    float a = acc[k];
    a += __shfl_xor(a, 1);
    a += __shfl_xor(a, 2);
    a += __shfl_xor(a, 4);
    a += __shfl_xor(a, 8);
    pk[k] = a + bias[nk[k]];
  }

  // --- fill indices: smallest absent set ids (SALU, 4x u64 presence mask) ---
  unsigned long long pm0 = 0, pm1 = 0, pm2 = 0, pm3 = 0;
#pragma unroll
  for (int k = 0; k < kK; ++k) {
    const bool v = (validmask >> k) & 1;
    const unsigned long long bit = 1ull << (nk[k] & 63);
    const int wd = nk[k] >> 6;
    pm0 |= (v && wd == 0) ? bit : 0ull;
    pm1 |= (v && wd == 1) ? bit : 0ull;
    pm2 |= (v && wd == 2) ? bit : 0ull;
    pm3 |= (v && wd == 3) ? bit : 0ull;
  }
  int seq[kK];
#pragma unroll
  for (int i = 0; i < kK; ++i) {
    const unsigned long long i0 = ~pm0, i1 = ~pm1, i2 = ~pm2, i3 = ~pm3;
    const int c = i0 ? (__ffsll(i0) - 1)
                     : (i1 ? 64 + (__ffsll(i1) - 1)
                           : (i2 ? 128 + (__ffsll(i2) - 1)
                                 : 192 + (__ffsll(i3) - 1)));
    seq[i] = c;
    const unsigned long long b2 = 1ull << (c & 63);
    const int wd = c >> 6;
    pm0 |= (wd == 0) ? b2 : 0ull;
    pm1 |= (wd == 1) ? b2 : 0ull;
    pm2 |= (wd == 2) ? b2 : 0ull;
    pm3 |= (wd == 3) ? b2 : 0ull;
  }

  // --- merge fills, Batcher-19 sort (desc score, asc idx), per group ---
  float fs[kK];
  int fi[kK];
#pragma unroll
  for (int k = 0; k < kK; ++k) {
    const bool v = (validmask >> k) & 1;
    const int jk = __popc((~validmask) & ((1 << k) - 1));
    int fv = seq[0];
#pragma unroll
    for (int j = 1; j < kK; ++j) fv = (jk == j) ? seq[j] : fv;
    fs[k] = v ? pk[k] : kNeg;
    fi[k] = v ? nk[k] : fv;
  }
#define CE(A, B)                                                        \
  {                                                                     \
    const bool sw = (fs[B] > fs[A]) || (fs[B] == fs[A] && fi[B] < fi[A]); \
    const float fa = fs[A], fb = fs[B];                                 \
    const int ia = fi[A], ib = fi[B];                                   \
    fs[A] = sw ? fb : fa; fs[B] = sw ? fa : fb;                         \
    fi[A] = sw ? ib : ia; fi[B] = sw ? ia : ib;                         \
  }
  CE(0,1) CE(2,3) CE(4,5) CE(6,7)
  CE(0,2) CE(1,3) CE(4,6) CE(5,7)
  CE(1,2) CE(5,6)
  CE(0,4) CE(1,5) CE(2,6) CE(3,7)
  CE(2,4) CE(3,5)
  CE(1,2) CE(3,4) CE(5,6)
#undef CE

  // --- softmax on sorted scores (fs[0] = max, valid = first cnt) ---
  const float it = kLog2e * FAST_RCP(fmaxf(temp_p[0], 0.5f));
  float w[kK];
  float denom = 0.f;
#pragma unroll
  for (int i = 0; i < kK; ++i) {
    const float e = (i < cnt) ? FAST_EXP2((fs[i] - fs[0]) * it) : 0.f;
    w[i] = e;
    denom += e;
  }
  const float rd = FAST_RCP(denom);
#pragma unroll
  for (int i = 0; i < kK; ++i) w[i] *= rd;

  // --- outputs: per group g -> row (g, s) ---
  const size_t row = (size_t)g * kS + s;
  if (u < kK) {
    int v = fi[0];
#pragma unroll
    for (int k = 1; k < kK; ++k) v = (u == k) ? fi[k] : v;
    out[kTopkOff + row * kK + u] = (float)v;
  }
  if (u == 0) out[kBankOff + row] = (float)fi[0];

  // state record: 16 dwords per row (8 weights bits + 8 indices); all lanes
  int sel = 0;
#pragma unroll
  for (int k = 0; k < kK; ++k) {
    sel = (u == k) ? __float_as_int(w[k]) : sel;
    sel = (u == k + kK) ? fi[k] : sel;
  }
  st[row * 16 + u] = sel;
}

// ---------------------------------------------------------------------------
// k_repr: one wave per token. s_load 64B state -> 32 ss gathers (L2-local,
// batch per XCD pair) -> token_repr + weights row. Tiny VGPR, max occupancy.
// ---------------------------------------------------------------------------
__global__ __launch_bounds__(256) void k_repr(const float* __restrict__ ss,
                                              const int* __restrict__ st,
                                              float* __restrict__ out) {
  const int lane = threadIdx.x & 63;
  const int wid = threadIdx.x >> 6;
  const int bid = blockIdx.x;
  const int xcd = bid & 7;
  const int b = xcd >> 1;
  int s_ = ((bid >> 3) << 2) + wid + ((xcd & 1) << 11);
  const int s = __builtin_amdgcn_readfirstlane(s_);
  const size_t row = (size_t)b * kS + s;

  // state (wave-uniform -> scalar loads)
  float w[kK];
  int fi[kK];
#pragma unroll
  for (int k = 0; k < kK; ++k) {
    w[k] = __int_as_float(st[row * 16 + k]);
    fi[k] = st[row * 16 + kK + k];
  }

  const float4* ssb = reinterpret_cast<const float4*>(ss) + (size_t)b * kN * (kD / 4);
  float4* o4 = reinterpret_cast<float4*>(out) + row * (kD / 4);
#pragma unroll
  for (int c = 0; c < 4; ++c) {
    float4 v0 = ssb[(size_t)fi[0] * (kD / 4) + c * 64 + lane];
    float4 v1 = ssb[(size_t)fi[1] * (kD / 4) + c * 64 + lane];
    float4 v2 = ssb[(size_t)fi[2] * (kD / 4) + c * 64 + lane];
    float4 v3 = ssb[(size_t)fi[3] * (kD / 4) + c * 64 + lane];
    float4 v4 = ssb[(size_t)fi[4] * (kD / 4) + c * 64 + lane];
    float4 v5 = ssb[(size_t)fi[5] * (kD / 4) + c * 64 + lane];
    float4 v6 = ssb[(size_t)fi[6] * (kD / 4) + c * 64 + lane];
    float4 v7 = ssb[(size_t)fi[7] * (kD / 4) + c * 64 + lane];
    float4 acc;
    acc.x = w[0] * v0.x + w[1] * v1.x + w[2] * v2.x + w[3] * v3.x
          + w[4] * v4.x + w[5] * v5.x + w[6] * v6.x + w[7] * v7.x;
    acc.y = w[0] * v0.y + w[1] * v1.y + w[2] * v2.y + w[3] * v3.y
          + w[4] * v4.y + w[5] * v5.y + w[6] * v6.y + w[7] * v7.y;
    acc.z = w[0] * v0.z + w[1] * v1.z + w[2] * v2.z + w[3] * v3.z
          + w[4] * v4.z + w[5] * v5.z + w[6] * v6.z + w[7] * v7.z;
    acc.w = w[0] * v0.w + w[1] * v1.w + w[2] * v2.w + w[3] * v3.w
          + w[4] * v4.w + w[5] * v5.w + w[6] * v6.w + w[7] * v7.w;
    o4[c * 64 + lane] = acc;
  }

  // weights row [N]: float4 per lane (fillers carry w==0 -> correct zeros)
  {
    const int cb = lane * 4;
    float4 wv = make_float4(0.f, 0.f, 0.f, 0.f);
#pragma unroll
    for (int k = 0; k < kK; ++k) {
      wv.x = (fi[k] == cb    ) ? w[k] : wv.x;
      wv.y = (fi[k] == cb + 1) ? w[k] : wv.y;
      wv.z = (fi[k] == cb + 2) ? w[k] : wv.z;
      wv.w = (fi[k] == cb + 3) ? w[k] : wv.w;
    }
    reinterpret_cast<float4*>(out + kWOff)[row * (kN / 4) + lane] = wv;
  }
}

extern "C" void kernel_launch(void* const* d_in, const int* in_sizes, int n_in,
                              void* d_out, int out_size, void* d_ws, size_t ws_size,
                              hipStream_t stream) {
  const float* ts  = (const float*)d_in[0];   // token_states [4,4096,1024]
  const float* ss  = (const float*)d_in[1];   // set_states   [4,256,1024]
  const float* dr  = (const float*)d_in[2];   // desc_router  [256,1024]
  const int*   t2s = (const int*)  d_in[3];   // token_to_sets[4096,8]
  const float* wq  = (const float*)d_in[4];   // Wq [1024,1024]
  const float* bq  = (const float*)d_in[5];   // bq [1024]
  const float* tmp = (const float*)d_in[6];   // temperature [1]
  float* out = (float*)d_out;

  float* R    = (float*)d_ws;                 // 256*1024 f32 = 1 MiB
  float* bias = R + (size_t)kN * kD;          // 256 f32
  int*   st   = (int*)(bias + kN);            // 16384 x 16 dwords = 1 MiB
  float* part = out + kWOff;                  // 8 MiB partials, overwritten by
                                              // k_repr's weights write later

  k_prep<<<dim3(kNT, kEC), 256, 0, stream>>>(dr, wq, part);
  k_reduce<<<kN, 256, 0, stream>>>(part, dr, bq, R, bias);
  k_score<<<kS / 4, 256, 0, stream>>>(ts, t2s, R, bias, tmp, st, out);
  k_repr<<<kB * kS / 4, 256, 0, stream>>>(ss, st, out);
}

// Round 8
// 72.086 us; speedup vs baseline: 1.2089x; 1.0793x over previous
//
#include <hip/hip_runtime.h>
#include <math.h>
#include <float.h>

// LearnedRouter: B=4, S=4096, D=1024, N=256, TOPK=8
// Outputs (concat, fp32): token_repr[B,S,D], bank_indices[B,S], weights[B,S,N], topk_idx[B,S,8]

namespace {
constexpr int kB = 4, kS = 4096, kD = 1024, kN = 256, kK = 8;
constexpr float kScale = 0.03125f;   // 1/sqrt(1024)
constexpr float kNeg = -1e9f;
constexpr float kLog2e = 1.4426950408889634f;
constexpr size_t kBankOff = (size_t)kB * kS * kD;            // 16777216
constexpr size_t kWOff    = kBankOff + (size_t)kB * kS;      // 16793600
constexpr size_t kTopkOff = kWOff + (size_t)kB * kS * kN;    // 20987904
constexpr int kEC = 8;           // e-chunks (K-split) in k_prep
constexpr int kEL = kD / kEC;    // 128 e per chunk
constexpr int kNT = kN / 8;      // 32 n-tiles of 8 rows
}

#if __has_builtin(__builtin_amdgcn_exp2f)
#define FAST_EXP2(x) __builtin_amdgcn_exp2f(x)
#else
#define FAST_EXP2(x) exp2f(x)
#endif
#if __has_builtin(__builtin_amdgcn_rcpf)
#define FAST_RCP(x) __builtin_amdgcn_rcpf(x)
#else
#define FAST_RCP(x) (1.0f / (x))
#endif

// ---------------------------------------------------------------------------
// k_prep: partial[ec][n][d] = sum_{e in chunk ec} dr[n,e] * Wq[e,d]
// ---------------------------------------------------------------------------
__global__ __launch_bounds__(256) void k_prep(const float* __restrict__ dr,
                                              const float* __restrict__ wq,
                                              float* __restrict__ part) {
  const int nt = blockIdx.x, ec = blockIdx.y, t = threadIdx.x;
  const float4* wq4 = reinterpret_cast<const float4*>(wq);   // [e][256]
  float4 acc[8];
#pragma unroll
  for (int j = 0; j < 8; ++j) acc[j] = make_float4(0.f, 0.f, 0.f, 0.f);
  const int e0 = ec * kEL;
#pragma unroll 4
  for (int e = e0; e < e0 + kEL; ++e) {
    const float4 wv = wq4[(size_t)e * (kD / 4) + t];
#pragma unroll
    for (int j = 0; j < 8; ++j) {
      const float a = dr[(size_t)(nt * 8 + j) * kD + e];   // uniform -> s_load
      acc[j].x += a * wv.x; acc[j].y += a * wv.y;
      acc[j].z += a * wv.z; acc[j].w += a * wv.w;
    }
  }
  float4* p4 = reinterpret_cast<float4*>(part);
#pragma unroll
  for (int j = 0; j < 8; ++j)
    p4[((size_t)ec * kN + nt * 8 + j) * (kD / 4) + t] = acc[j];
}

// ---------------------------------------------------------------------------
// k_reduce: R[n][d] = kScale * sum_ec partial[ec][n][d];  bias[n] likewise.
// ---------------------------------------------------------------------------
__global__ __launch_bounds__(256) void k_reduce(const float* __restrict__ part,
                                                const float* __restrict__ dr,
                                                const float* __restrict__ bq,
                                                float* __restrict__ R,
                                                float* __restrict__ bias) {
  const int n = blockIdx.x, t = threadIdx.x;
  const float4* p4 = reinterpret_cast<const float4*>(part);
  float4 a = make_float4(0.f, 0.f, 0.f, 0.f);
#pragma unroll
  for (int ec = 0; ec < kEC; ++ec) {
    const float4 p = p4[((size_t)ec * kN + n) * (kD / 4) + t];
    a.x += p.x; a.y += p.y; a.z += p.z; a.w += p.w;
  }
  a.x *= kScale; a.y *= kScale; a.z *= kScale; a.w *= kScale;
  reinterpret_cast<float4*>(R)[(size_t)n * (kD / 4) + t] = a;

  if (t < 64) {
    const float4* b4 = reinterpret_cast<const float4*>(bq);
    const float4* dr4 = reinterpret_cast<const float4*>(dr + (size_t)n * kD);
    float p = 0.f;
#pragma unroll
    for (int i = 0; i < 4; ++i) {
      const float4 bb = b4[t * 4 + i];
      const float4 dd = dr4[t * 4 + i];
      p += bb.x * dd.x + bb.y * dd.y + bb.z * dd.z + bb.w * dd.w;
    }
#pragma unroll
    for (int off = 32; off; off >>= 1) p += __shfl_xor(p, off);
    if (t == 0) bias[n] = p * kScale;
  }
}

// ---------------------------------------------------------------------------
// k_score v3b: ONE WAVE (64 thr) PER TOKEN POSITION, transposed full-wave dot.
// All loads full-wave 1KB dwordx4: 16 ts + 32 R (double-buffered) = 48
// VMEM/wave. Per-lane partials acc[t][k] -> within-16 butterfly (partials
// P(t,grp) on every lane) -> batch-major cross-group combine:
//   y = acc[g] + shfl16(acc[g^1]);  z = acc[g^2] + shfl16(acc[g^3]);
//   pk = y + shfl32(z)
// (partner evaluates its selects with ITS g, which lands exactly on our
// batch -- verified by lane trace; R7 bug was summing mixed batches).
// ---------------------------------------------------------------------------
__global__ __launch_bounds__(64, 3) void k_score(const float* __restrict__ ts,
                                                 const int* __restrict__ t2s,
                                                 const float* __restrict__ R,
                                                 const float* __restrict__ bias,
                                                 const float* __restrict__ temp_p,
                                                 int* __restrict__ st,
                                                 float* __restrict__ out) {
  const int lane = threadIdx.x;
  const int u = lane & 15;     // slot within group
  const int g = lane >> 4;     // batch of this lane's tail work
  const int s = blockIdx.x;    // token position (SGPR)

  // --- routing indices (SALU/SMEM, shared by all 4 batches) ---
  int nraw[kK], nk[kK];
#pragma unroll
  for (int k = 0; k < kK; ++k) {
    nraw[k] = t2s[s * kK + k];
    const int n = nraw[k];
    nk[k] = n < 0 ? 0 : (n > kN - 1 ? kN - 1 : n);
  }
  int validmask = 0;
#pragma unroll
  for (int k = 0; k < kK; ++k) {
    bool v = (nraw[k] >= 0);
#pragma unroll
    for (int j = 0; j < kK; ++j)
      if (j < k && nk[j] == nk[k]) v = false;
    validmask |= v ? (1 << k) : 0;
  }
  const int cnt = __popc(validmask);

  // --- full-wave ts loads: 4 batches x 4 chunks, 1KB each ---
  const float4* ts4 = reinterpret_cast<const float4*>(ts);
  const float4* R4 = reinterpret_cast<const float4*>(R);
  float4 tv[kB][4];
#pragma unroll
  for (int t = 0; t < kB; ++t)
#pragma unroll
    for (int j = 0; j < 4; ++j)
      tv[t][j] = ts4[((size_t)t * kS + s) * (kD / 4) + j * 64 + lane];

  // --- per-row phases, double-buffered R loads, per-lane partials ---
  float acc[kB][kK];
  float4 rc[4];
#pragma unroll
  for (int j = 0; j < 4; ++j)
    rc[j] = R4[(size_t)nk[0] * (kD / 4) + j * 64 + lane];
#pragma unroll
  for (int k = 0; k < kK; ++k) {
    float4 rn[4];
    if (k + 1 < kK) {
#pragma unroll
      for (int j = 0; j < 4; ++j)
        rn[j] = R4[(size_t)nk[k + 1] * (kD / 4) + j * 64 + lane];
    }
#pragma unroll
    for (int t = 0; t < kB; ++t) {
      float a = tv[t][0].x * rc[0].x + tv[t][0].y * rc[0].y
              + tv[t][0].z * rc[0].z + tv[t][0].w * rc[0].w;
      a += tv[t][1].x * rc[1].x + tv[t][1].y * rc[1].y
         + tv[t][1].z * rc[1].z + tv[t][1].w * rc[1].w;
      a += tv[t][2].x * rc[2].x + tv[t][2].y * rc[2].y
         + tv[t][2].z * rc[2].z + tv[t][2].w * rc[2].w;
      a += tv[t][3].x * rc[3].x + tv[t][3].y * rc[3].y
         + tv[t][3].z * rc[3].z + tv[t][3].w * rc[3].w;
      acc[t][k] = a;
    }
    if (k + 1 < kK) {
#pragma unroll
      for (int j = 0; j < 4; ++j) rc[j] = rn[j];
    }
  }

  // --- within-16 butterfly: every lane gets P(t, grp) for all t ---
#pragma unroll
  for (int t = 0; t < kB; ++t)
#pragma unroll
    for (int k = 0; k < kK; ++k) {
      float a = acc[t][k];
      a += __shfl_xor(a, 1);
      a += __shfl_xor(a, 2);
      a += __shfl_xor(a, 4);
      a += __shfl_xor(a, 8);
      acc[t][k] = a;
    }

  // --- batch-major cross-group combine (bug-fixed) ---
  float pk[kK];
#pragma unroll
  for (int k = 0; k < kK; ++k) {
    const float a0 = acc[0][k], a1 = acc[1][k], a2 = acc[2][k], a3 = acc[3][k];
    float own = a0; own = (g == 1) ? a1 : own; own = (g == 2) ? a2 : own; own = (g == 3) ? a3 : own;  // acc[g]
    float x1  = a1; x1  = (g == 1) ? a0 : x1;  x1  = (g == 2) ? a3 : x1;  x1  = (g == 3) ? a2 : x1;   // acc[g^1]
    float x2  = a2; x2  = (g == 1) ? a3 : x2;  x2  = (g == 2) ? a0 : x2;  x2  = (g == 3) ? a1 : x2;   // acc[g^2]
    float x3  = a3; x3  = (g == 1) ? a2 : x3;  x3  = (g == 2) ? a1 : x3;  x3  = (g == 3) ? a0 : x3;   // acc[g^3]
    const float y = own + __shfl_xor(x1, 16);
    const float z = x2 + __shfl_xor(x3, 16);
    pk[k] = y + __shfl_xor(z, 32) + bias[nk[k]];
  }

  // --- fill indices: smallest absent set ids (SALU, 4x u64 presence mask) ---
  unsigned long long pm0 = 0, pm1 = 0, pm2 = 0, pm3 = 0;
#pragma unroll
  for (int k = 0; k < kK; ++k) {
    const bool v = (validmask >> k) & 1;
    const unsigned long long bit = 1ull << (nk[k] & 63);
    const int wd = nk[k] >> 6;
    pm0 |= (v && wd == 0) ? bit : 0ull;
    pm1 |= (v && wd == 1) ? bit : 0ull;
    pm2 |= (v && wd == 2) ? bit : 0ull;
    pm3 |= (v && wd == 3) ? bit : 0ull;
  }
  int seq[kK];
#pragma unroll
  for (int i = 0; i < kK; ++i) {
    const unsigned long long i0 = ~pm0, i1 = ~pm1, i2 = ~pm2, i3 = ~pm3;
    const int c = i0 ? (__ffsll(i0) - 1)
                     : (i1 ? 64 + (__ffsll(i1) - 1)
                           : (i2 ? 128 + (__ffsll(i2) - 1)
                                 : 192 + (__ffsll(i3) - 1)));
    seq[i] = c;
    const unsigned long long b2 = 1ull << (c & 63);
    const int wd = c >> 6;
    pm0 |= (wd == 0) ? b2 : 0ull;
    pm1 |= (wd == 1) ? b2 : 0ull;
    pm2 |= (wd == 2) ? b2 : 0ull;
    pm3 |= (wd == 3) ? b2 : 0ull;
  }

  // --- merge fills, Batcher-19 sort (desc score, asc idx), per lane ---
  float fs[kK];
  int fi[kK];
#pragma unroll
  for (int k = 0; k < kK; ++k) {
    const bool v = (validmask >> k) & 1;
    const int jk = __popc((~validmask) & ((1 << k) - 1));
    int fv = seq[0];
#pragma unroll
    for (int j = 1; j < kK; ++j) fv = (jk == j) ? seq[j] : fv;
    fs[k] = v ? pk[k] : kNeg;
    fi[k] = v ? nk[k] : fv;
  }
#define CE(A, B)                                                        \
  {                                                                     \
    const bool sw = (fs[B] > fs[A]) || (fs[B] == fs[A] && fi[B] < fi[A]); \
    const float fa = fs[A], fb = fs[B];                                 \
    const int ia = fi[A], ib = fi[B];                                   \
    fs[A] = sw ? fb : fa; fs[B] = sw ? fa : fb;                         \
    fi[A] = sw ? ib : ia; fi[B] = sw ? ia : ib;                         \
  }
  CE(0,1) CE(2,3) CE(4,5) CE(6,7)
  CE(0,2) CE(1,3) CE(4,6) CE(5,7)
  CE(1,2) CE(5,6)
  CE(0,4) CE(1,5) CE(2,6) CE(3,7)
  CE(2,4) CE(3,5)
  CE(1,2) CE(3,4) CE(5,6)
#undef CE

  // --- softmax on sorted scores (fs[0] = max, valid = first cnt) ---
  const float it = kLog2e * FAST_RCP(fmaxf(temp_p[0], 0.5f));
  float w[kK];
  float denom = 0.f;
#pragma unroll
  for (int i = 0; i < kK; ++i) {
    const float e = (i < cnt) ? FAST_EXP2((fs[i] - fs[0]) * it) : 0.f;
    w[i] = e;
    denom += e;
  }
  const float rd = FAST_RCP(denom);
#pragma unroll
  for (int i = 0; i < kK; ++i) w[i] *= rd;

  // --- outputs: lane group g -> row (g, s) ---
  const size_t row = (size_t)g * kS + s;
  if (u < kK) {
    int v = fi[0];
#pragma unroll
    for (int k = 1; k < kK; ++k) v = (u == k) ? fi[k] : v;
    out[kTopkOff + row * kK + u] = (float)v;
  }
  if (u == 0) out[kBankOff + row] = (float)fi[0];

  // state record: 16 dwords per row (8 weight bits + 8 indices)
  int sel = 0;
#pragma unroll
  for (int k = 0; k < kK; ++k) {
    sel = (u == k) ? __float_as_int(w[k]) : sel;
    sel = (u == k + kK) ? fi[k] : sel;
  }
  st[row * 16 + u] = sel;
}

// ---------------------------------------------------------------------------
// k_repr: one wave per token. s_load 64B state -> 32 ss gathers (L2-local,
// batch per XCD pair) -> token_repr + weights row. Tiny VGPR, max occupancy.
// ---------------------------------------------------------------------------
__global__ __launch_bounds__(256) void k_repr(const float* __restrict__ ss,
                                              const int* __restrict__ st,
                                              float* __restrict__ out) {
  const int lane = threadIdx.x & 63;
  const int wid = threadIdx.x >> 6;
  const int bid = blockIdx.x;
  const int xcd = bid & 7;
  const int b = xcd >> 1;
  int s_ = ((bid >> 3) << 2) + wid + ((xcd & 1) << 11);
  const int s = __builtin_amdgcn_readfirstlane(s_);
  const size_t row = (size_t)b * kS + s;

  // state (wave-uniform -> scalar loads)
  float w[kK];
  int fi[kK];
#pragma unroll
  for (int k = 0; k < kK; ++k) {
    w[k] = __int_as_float(st[row * 16 + k]);
    fi[k] = st[row * 16 + kK + k];
  }

  const float4* ssb = reinterpret_cast<const float4*>(ss) + (size_t)b * kN * (kD / 4);
  float4* o4 = reinterpret_cast<float4*>(out) + row * (kD / 4);
#pragma unroll
  for (int c = 0; c < 4; ++c) {
    float4 v0 = ssb[(size_t)fi[0] * (kD / 4) + c * 64 + lane];
    float4 v1 = ssb[(size_t)fi[1] * (kD / 4) + c * 64 + lane];
    float4 v2 = ssb[(size_t)fi[2] * (kD / 4) + c * 64 + lane];
    float4 v3 = ssb[(size_t)fi[3] * (kD / 4) + c * 64 + lane];
    float4 v4 = ssb[(size_t)fi[4] * (kD / 4) + c * 64 + lane];
    float4 v5 = ssb[(size_t)fi[5] * (kD / 4) + c * 64 + lane];
    float4 v6 = ssb[(size_t)fi[6] * (kD / 4) + c * 64 + lane];
    float4 v7 = ssb[(size_t)fi[7] * (kD / 4) + c * 64 + lane];
    float4 acc;
    acc.x = w[0] * v0.x + w[1] * v1.x + w[2] * v2.x + w[3] * v3.x
          + w[4] * v4.x + w[5] * v5.x + w[6] * v6.x + w[7] * v7.x;
    acc.y = w[0] * v0.y + w[1] * v1.y + w[2] * v2.y + w[3] * v3.y
          + w[4] * v4.y + w[5] * v5.y + w[6] * v6.y + w[7] * v7.y;
    acc.z = w[0] * v0.z + w[1] * v1.z + w[2] * v2.z + w[3] * v3.z
          + w[4] * v4.z + w[5] * v5.z + w[6] * v6.z + w[7] * v7.z;
    acc.w = w[0] * v0.w + w[1] * v1.w + w[2] * v2.w + w[3] * v3.w
          + w[4] * v4.w + w[5] * v5.w + w[6] * v6.w + w[7] * v7.w;
    o4[c * 64 + lane] = acc;
  }

  // weights row [N]: float4 per lane (fillers carry w==0 -> correct zeros)
  {
    const int cb = lane * 4;
    float4 wv = make_float4(0.f, 0.f, 0.f, 0.f);
#pragma unroll
    for (int k = 0; k < kK; ++k) {
      wv.x = (fi[k] == cb    ) ? w[k] : wv.x;
      wv.y = (fi[k] == cb + 1) ? w[k] : wv.y;
      wv.z = (fi[k] == cb + 2) ? w[k] : wv.z;
      wv.w = (fi[k] == cb + 3) ? w[k] : wv.w;
    }
    reinterpret_cast<float4*>(out + kWOff)[row * (kN / 4) + lane] = wv;
  }
}

extern "C" void kernel_launch(void* const* d_in, const int* in_sizes, int n_in,
                              void* d_out, int out_size, void* d_ws, size_t ws_size,
                              hipStream_t stream) {
  const float* ts  = (const float*)d_in[0];   // token_states [4,4096,1024]
  const float* ss  = (const float*)d_in[1];   // set_states   [4,256,1024]
  const float* dr  = (const float*)d_in[2];   // desc_router  [256,1024]
  const int*   t2s = (const int*)  d_in[3];   // token_to_sets[4096,8]
  const float* wq  = (const float*)d_in[4];   // Wq [1024,1024]
  const float* bq  = (const float*)d_in[5];   // bq [1024]
  const float* tmp = (const float*)d_in[6];   // temperature [1]
  float* out = (float*)d_out;

  float* R    = (float*)d_ws;                 // 256*1024 f32 = 1 MiB
  float* bias = R + (size_t)kN * kD;          // 256 f32
  int*   st   = (int*)(bias + kN);            // 16384 x 16 dwords = 1 MiB
  float* part = out + kWOff;                  // 8 MiB partials, overwritten by
                                              // k_repr's weights write later

  k_prep<<<dim3(kNT, kEC), 256, 0, stream>>>(dr, wq, part);
  k_reduce<<<kN, 256, 0, stream>>>(part, dr, bq, R, bias);
  k_score<<<kS, 64, 0, stream>>>(ts, t2s, R, bias, tmp, st, out);
  k_repr<<<kB * kS / 4, 256, 0, stream>>>(ss, st, out);
}